// Round 10
// baseline (366.781 us; speedup 1.0000x reference)
//
#include <hip/hip_runtime.h>
#include <hip/hip_fp16.h>

#define NPTS 100000
#define NB 500
#define KNN 100
#define KPN 15
#define C1 128
#define C2 1024
#define C3 512
#define C4 256

// ---- L-inf kNN grid parameters
#define G 64
#define NCELLS (G * G * G)
#define GB 5.0f
#define GINVH ((float)G / (2.f * GB))  // 6.4 cells per unit
#define CAND_CAP 2048

typedef _Float16 half8 __attribute__((ext_vector_type(8)));
typedef float f32x4 __attribute__((ext_vector_type(4)));

// ------------------------------------------------- grid helpers
__device__ __forceinline__ int cell_coord(float x) {
  int c = (int)floorf((x + GB) * GINVH);
  return min(max(c, 0), G - 1);
}
__device__ __forceinline__ int cell_of(float x, float y, float z) {
  return (cell_coord(x) << 12) | (cell_coord(y) << 6) | cell_coord(z);
}

// ------ prep: gather + converts (conv1/kpw/fc1w/fc2w hi-lo) + grid hist
__global__ __launch_bounds__(256) void prep_kernel(
    const float* __restrict__ pts, const float* __restrict__ normal,
    const int* __restrict__ index, const float* __restrict__ w1,
    const float* __restrict__ kpw, const float* __restrict__ fc1w,
    const float* __restrict__ fc2w, float* __restrict__ sel,
    float* __restrict__ out2, __half* __restrict__ wh,
    __half* __restrict__ kpwT_hi, __half* __restrict__ kpwT_lo,
    __half* __restrict__ fwhi, __half* __restrict__ fwlo,
    __half* __restrict__ f2whi, __half* __restrict__ f2wlo,
    unsigned* __restrict__ cnt) {
  int i = blockIdx.x * 256 + threadIdx.x;
  if (i < NB) {
    int ix = index[i];
    sel[i * 3 + 0] = pts[3 * ix + 0];
    sel[i * 3 + 1] = pts[3 * ix + 1];
    sel[i * 3 + 2] = pts[3 * ix + 2];
    out2[i * 3 + 0] = normal[3 * ix + 0];
    out2[i * 3 + 1] = normal[3 * ix + 1];
    out2[i * 3 + 2] = normal[3 * ix + 2];
  }
  if (i < C2 * C1) wh[i] = __float2half(w1[i]);
  if (i < 128 * 64) {
    int o = i >> 6, j = i & 63;
    float v = (j < 45) ? kpw[j * 128 + o] : 0.f;
    __half hi = __float2half_rn(v);
    kpwT_hi[i] = hi;
    kpwT_lo[i] = __float2half_rn(v - __half2float(hi));
  }
  if (i < C3 * C2) {
    float v = fc1w[i];
    __half hi = __float2half_rn(v);
    fwhi[i] = hi;
    fwlo[i] = __float2half_rn(v - __half2float(hi));
  }
  if (i < C4 * C3) {
    float v = fc2w[i];
    __half hi = __float2half_rn(v);
    f2whi[i] = hi;
    f2wlo[i] = __float2half_rn(v - __half2float(hi));
  }
  if (i < NPTS)
    atomicAdd(&cnt[cell_of(pts[3 * i], pts[3 * i + 1], pts[3 * i + 2])], 1u);
}

// --------------- grid scan: single kernel, atomic chunk-base assignment
// Only per-cell contiguity/disjointness of [end-cnt,end) matters to the
// consumers (scatter atomically fills within segment; knn reads segment
// bounds) -- global cell ordering is irrelevant, so chunk bases may be
// assigned in atomic arrival order. Replaces the 3-stage scan.
__global__ __launch_bounds__(256) void grid_scan_kernel(
    const unsigned* __restrict__ cnt, unsigned* __restrict__ cursor,
    unsigned* __restrict__ gbase) {
  const int tid = threadIdx.x;
  int base = blockIdx.x * 1024 + tid * 4;
  unsigned c0 = cnt[base], c1 = cnt[base + 1], c2 = cnt[base + 2],
           c3 = cnt[base + 3];
  unsigned tot = c0 + c1 + c2 + c3;
  __shared__ unsigned sb[256];
  __shared__ unsigned s_base;
  sb[tid] = tot;
  __syncthreads();
  for (int off = 1; off < 256; off <<= 1) {
    unsigned add = (tid >= off) ? sb[tid - off] : 0u;
    __syncthreads();
    sb[tid] += add;
    __syncthreads();
  }
  if (tid == 255) s_base = atomicAdd(gbase, sb[255]);
  __syncthreads();
  unsigned excl = s_base + sb[tid] - tot;
  cursor[base] = excl;
  cursor[base + 1] = excl + c0;
  cursor[base + 2] = excl + c0 + c1;
  cursor[base + 3] = excl + c0 + c1 + c2;
}

// scatter: cursor turns into per-cell END offsets; begin = end - cnt
__global__ __launch_bounds__(256) void grid_scatter_kernel(
    const float* __restrict__ pts, unsigned* __restrict__ cursor,
    float4* __restrict__ sorted) {
  int i = blockIdx.x * 256 + threadIdx.x;
  if (i >= NPTS) return;
  float x = pts[3 * i], y = pts[3 * i + 1], z = pts[3 * i + 2];
  unsigned pos = atomicAdd(&cursor[cell_of(x, y, z)], 1u);
  sorted[pos] = make_float4(x, y, z, __int_as_float(i));
}

// ---------------------------------------------------------------- kNN v7
// v7: when the exact cover cube (from dub) is nested inside the Phase-A
// collect cube and no LDS overflow occurred, Phase C is skipped: the
// Phase-B candidate set already contains every point with bits < bub, and
// rank-select over the unfiltered set is exact (elements >= bub have rank
// >= KNN; they cannot alter ranks of smaller elements).
__device__ __forceinline__ unsigned linf_bits(float px, float py, float pz,
                                              float sx, float sy, float sz) {
  float dx = fabsf(px - sx), dy = fabsf(py - sy), dz = fabsf(pz - sz);
  return __float_as_uint(fmaxf(fmaxf(dx, dy), dz));
}

__global__ __launch_bounds__(256) void knn_kernel(
    const float4* __restrict__ sorted, const unsigned* __restrict__ cnt,
    const unsigned* __restrict__ cursor,  // per-cell end offsets
    const float* __restrict__ sel, int* __restrict__ nbr) {
  const int b = blockIdx.x;
  const int tid = threadIdx.x;
  __shared__ unsigned cbits[CAND_CAP];
  __shared__ int cidx[CAND_CAP];
  __shared__ unsigned hist[4096];
  __shared__ unsigned scanbuf[256];
  __shared__ int s_total, s_m, s_mc, s_chunk;
  __shared__ unsigned s_excl, s_bub;

  const float qx = sel[b * 3 + 0], qy = sel[b * 3 + 1], qz = sel[b * 3 + 2];
  const int qcx = cell_coord(qx), qcy = cell_coord(qy), qcz = cell_coord(qz);

  // ---------------- Phase A: expand cube until >=KNN (shell-incremental)
  if (tid == 0) s_total = 0;
  __syncthreads();
  int s = 1;
  int pxlo = 1, pxhi = 0, pylo = 1, pyhi = 0, pzlo = 1, pzhi = 0;  // empty
  int xlo, xhi, ylo, yhi, zlo, zhi;
  for (;;) {
    xlo = max(qcx - s, 0); xhi = min(qcx + s, G - 1);
    ylo = max(qcy - s, 0); yhi = min(qcy + s, G - 1);
    zlo = max(qcz - s, 0); zhi = min(qcz + s, G - 1);
    int nx = xhi - xlo + 1, ny = yhi - ylo + 1, nz = zhi - zlo + 1;
    int ncell = nx * ny * nz;
    unsigned local = 0;
    for (int ci = tid; ci < ncell; ci += 256) {
      int cz = ci % nz;
      int r = ci / nz;
      int cy = r % ny;
      int cx = r / ny;
      int ax = xlo + cx, ay = ylo + cy, az = zlo + cz;
      if (ax >= pxlo && ax <= pxhi && ay >= pylo && ay <= pyhi &&
          az >= pzlo && az <= pzhi)
        continue;  // interior (already counted)
      local += cnt[(ax << 12) | (ay << 6) | az];
    }
#pragma unroll
    for (int off = 32; off; off >>= 1) local += __shfl_down(local, off);
    if ((tid & 63) == 0) atomicAdd(&s_total, (int)local);
    __syncthreads();
    if (s_total >= KNN || (xlo == 0 && ylo == 0 && zlo == 0 && xhi == G - 1 &&
                           yhi == G - 1 && zhi == G - 1))
      break;
    pxlo = xlo; pxhi = xhi; pylo = ylo; pyhi = yhi; pzlo = zlo; pzhi = zhi;
    ++s;
    __syncthreads();
  }

  // ---------------- Phase B: collect cube points (per-cell batched slots)
  if (tid == 0) s_m = 0;
  __syncthreads();
  {
    int nx = xhi - xlo + 1, ny = yhi - ylo + 1, nz = zhi - zlo + 1;
    int ncell = nx * ny * nz;
    for (int ci = tid; ci < ncell; ci += 256) {
      int cz = ci % nz;
      int r = ci / nz;
      int cy = r % ny;
      int cx = r / ny;
      int cell = ((xlo + cx) << 12) | ((ylo + cy) << 6) | (zlo + cz);
      unsigned end = cursor[cell];
      unsigned beg = end - cnt[cell];
      int k = (int)(end - beg);
      if (k > 0) {
        int e0 = atomicAdd(&s_m, k);
        for (unsigned p = beg; p < end; ++p, ++e0) {
          if (e0 < CAND_CAP) {
            float4 f = sorted[p];
            cbits[e0] = linf_bits(f.x, f.y, f.z, qx, qy, qz);
            cidx[e0] = __float_as_int(f.w);
          }
        }
      }
    }
  }
  __syncthreads();
  int m = s_m < CAND_CAP ? s_m : CAND_CAP;

  // ---------------- histogram select: upper bound on 100th distance
  for (int j = tid; j < 4096; j += 256) hist[j] = 0;
  __syncthreads();
  for (int e = tid; e < m; e += 256) atomicAdd(&hist[cbits[e] >> 19], 1u);
  __syncthreads();
  unsigned csum = 0;
  {
    int c0 = tid * 16;
#pragma unroll
    for (int j = 0; j < 16; ++j) csum += hist[c0 + j];
  }
  scanbuf[tid] = csum;
  __syncthreads();
  for (int off = 1; off < 256; off <<= 1) {
    unsigned add = (tid >= off) ? scanbuf[tid - off] : 0u;
    __syncthreads();
    scanbuf[tid] += add;
    __syncthreads();
  }
  {
    unsigned incl = scanbuf[tid], excl = incl - csum;
    if (excl < KNN && KNN <= incl) {
      s_chunk = tid;
      s_excl = excl;
    }
  }
  __syncthreads();
  if (tid == 0) {
    unsigned cum = s_excl;
    int bin = s_chunk * 16;
    while (cum + hist[bin] < KNN) {
      cum += hist[bin];
      ++bin;
    }
    s_bub = (unsigned)(bin + 1) << 19;  // exclusive upper bound on bits
  }
  __syncthreads();

  // ---------------- Phase C: exact cover cube (skipped when nested)
  const unsigned bub = s_bub;
  const float dub = __uint_as_float(bub);
  int xlo2 = min(max((int)floorf((qx - dub + GB) * GINVH), 0), G - 1);
  int xhi2 = min(max((int)floorf((qx + dub + GB) * GINVH), 0), G - 1);
  int ylo2 = min(max((int)floorf((qy - dub + GB) * GINVH), 0), G - 1);
  int yhi2 = min(max((int)floorf((qy + dub + GB) * GINVH), 0), G - 1);
  int zlo2 = min(max((int)floorf((qz - dub + GB) * GINVH), 0), G - 1);
  int zhi2 = min(max((int)floorf((qz + dub + GB) * GINVH), 0), G - 1);
  const bool nested = (s_m <= CAND_CAP) && xlo2 >= xlo && xhi2 <= xhi &&
                      ylo2 >= ylo && yhi2 <= yhi && zlo2 >= zlo && zhi2 <= zhi;

  int mc;
  if (nested) {
    // Phase-B set is a superset of all points with bits < bub; rank-select
    // over it directly (elements >= bub land at rank >= KNN, never written).
    mc = m;
  } else {
    if (tid == 0) s_mc = 0;
    __syncthreads();
    {
      int nx = xhi2 - xlo2 + 1, ny = yhi2 - ylo2 + 1, nz = zhi2 - zlo2 + 1;
      int ncell = nx * ny * nz;
      for (int ci = tid; ci < ncell; ci += 256) {
        int cz = ci % nz;
        int r = ci / nz;
        int cy = r % ny;
        int cx = r / ny;
        int cell = ((xlo2 + cx) << 12) | ((ylo2 + cy) << 6) | (zlo2 + cz);
        unsigned end = cursor[cell];
        unsigned beg = end - cnt[cell];
        for (unsigned p = beg; p < end; ++p) {
          float4 f = sorted[p];
          unsigned bits = linf_bits(f.x, f.y, f.z, qx, qy, qz);
          if (bits < bub) {
            int e = atomicAdd(&s_mc, 1);
            if (e < CAND_CAP) {
              cbits[e] = bits;
              cidx[e] = __float_as_int(f.w);
            }
          }
        }
      }
    }
    __syncthreads();
    mc = s_mc < CAND_CAP ? s_mc : CAND_CAP;
  }

  // ---------------- exact rank-select (ties by original index, stable)
  for (int c = tid; c < mc; c += 256) {
    unsigned bc = cbits[c];
    int ic = cidx[c];
    int rank = 0;
    for (int j = 0; j < mc; ++j) {
      unsigned bj = cbits[j];
      rank += (bj < bc || (bj == bc && cidx[j] < ic)) ? 1 : 0;
    }
    if (rank < KNN) nbr[b * KNN + rank] = ic;
  }
}

// ---------------------------- KPConv + conv1 FUSED (f16 MFMA, 8 waves)
// v4: per-(b,col) stats stored once (no 500-way atomic contention);
// stats1_kernel reduces. Phase-2 LDS-free (A-frags in regs, B from L2).
__global__ __launch_bounds__(512, 2) void kpconv_conv1_kernel(
    const float* __restrict__ pts, const float* __restrict__ sel,
    const int* __restrict__ nbr, const float* __restrict__ kp_points,
    const __half* __restrict__ kpwT_hi, const __half* __restrict__ kpwT_lo,
    const float* __restrict__ kp_sigma, const __half* __restrict__ wh,
    const float* __restrict__ bias, float* __restrict__ featmax,
    float* __restrict__ featmin, float* __restrict__ featsum,
    float* __restrict__ featsq) {
  const int b = blockIdx.x;
  const int tid = threadIdx.x;
  const int wave = tid >> 6, lane = tid & 63;
  const int lr = lane & 15, quad = lane >> 4;

  __shared__ __align__(16) char smem[71168];
  // phase-1 carve
  __half* As_hi = (__half*)smem;            // 112*72
  __half* As_lo = As_hi + 112 * 72;
  __half* Bs_hi = As_lo + 112 * 72;         // 128*72
  __half* Bs_lo = Bs_hi + 128 * 72;
  float* rel = (float*)(Bs_lo + 128 * 72);  // 100*4
  float* kpp = rel + 100 * 4;               // 48
  // phase-2 overlay: Hs only
  __half* Hs = (__half*)smem;               // 112*136

  // ---- phase 1 staging
  for (int i = tid; i < 128 * 8; i += 512) {
    int row = i >> 3, seg = i & 7;
    *(float4*)&Bs_hi[row * 72 + seg * 8] =
        *(const float4*)&kpwT_hi[row * 64 + seg * 8];
    *(float4*)&Bs_lo[row * 72 + seg * 8] =
        *(const float4*)&kpwT_lo[row * 64 + seg * 8];
  }
  {
    float4 z = make_float4(0.f, 0.f, 0.f, 0.f);
    for (int i = tid; i < 112 * 8; i += 512) {
      int row = i >> 3, seg = i & 7;
      *(float4*)&As_hi[row * 72 + seg * 8] = z;
      *(float4*)&As_lo[row * 72 + seg * 8] = z;
    }
  }
  if (tid < 45) kpp[tid] = kp_points[tid];
  if (tid < 100) {
    int idx = nbr[b * KNN + tid];
    rel[tid * 4 + 0] = pts[3 * idx + 0] - sel[b * 3 + 0];
    rel[tid * 4 + 1] = pts[3 * idx + 1] - sel[b * 3 + 1];
    rel[tid * 4 + 2] = pts[3 * idx + 2] - sel[b * 3 + 2];
  }
  __syncthreads();

  const float sg = kp_sigma[0];
  const float inv2s2 = -0.5f / (sg * sg);
  for (int i = tid; i < 100 * KPN; i += 512) {
    int k = i / KPN, p = i - k * KPN;
    float rx = rel[k * 4 + 0] - kpp[p * 3 + 0];
    float ry = rel[k * 4 + 1] - kpp[p * 3 + 1];
    float rz = rel[k * 4 + 2] - kpp[p * 3 + 2];
    float w = expf(inv2s2 * (rx * rx + ry * ry + rz * rz));
#pragma unroll
    for (int c = 0; c < 3; ++c) {
      float a = rel[k * 4 + c] * w;
      __half hi = __float2half_rn(a);
      As_hi[k * 72 + p * 3 + c] = hi;
      As_lo[k * 72 + p * 3 + c] = __float2half_rn(a - __half2float(hi));
    }
  }
  __syncthreads();

  // ---- phase 1 MFMA: acc = Ahi*Bhi + Ahi*Blo + Alo*Bhi (wave owns tile w)
  f32x4 acc1[7];
#pragma unroll
  for (int m = 0; m < 7; ++m) acc1[m] = (f32x4)(0.f);
#pragma unroll
  for (int s = 0; s < 2; ++s) {
    int boff = (wave * 16 + lr) * 72 + s * 32 + quad * 8;
    half8 bhi = *(const half8*)&Bs_hi[boff];
    half8 blo = *(const half8*)&Bs_lo[boff];
#pragma unroll
    for (int m = 0; m < 7; ++m) {
      int aoff = (m * 16 + lr) * 72 + s * 32 + quad * 8;
      half8 ahi = *(const half8*)&As_hi[aoff];
      half8 alo = *(const half8*)&As_lo[aoff];
      acc1[m] = __builtin_amdgcn_mfma_f32_16x16x32_f16(ahi, bhi, acc1[m], 0, 0, 0);
      acc1[m] = __builtin_amdgcn_mfma_f32_16x16x32_f16(ahi, blo, acc1[m], 0, 0, 0);
      acc1[m] = __builtin_amdgcn_mfma_f32_16x16x32_f16(alo, bhi, acc1[m], 0, 0, 0);
    }
  }
  __syncthreads();  // As/Bs dead; safe to overlay Hs

  // ---- write h tile to LDS (rows>=100 zero: As rows were zeroed)
  {
    int col = wave * 16 + lr;
#pragma unroll
    for (int m = 0; m < 7; ++m)
#pragma unroll
      for (int r = 0; r < 4; ++r) {
        int row = m * 16 + quad * 4 + r;
        Hs[row * 136 + col] = __float2half_rn(fmaxf(acc1[m][r], 0.f));
      }
  }
  __syncthreads();  // Hs complete (cross-wave cols)

  // ---- cache all A-fragments in registers (one-time LDS read)
  half8 afr[4][7];
#pragma unroll
  for (int s = 0; s < 4; ++s)
#pragma unroll
    for (int m = 0; m < 7; ++m)
      afr[s][m] = *(const half8*)&Hs[(m * 16 + lr) * 136 + s * 32 + quad * 8];

  // ---- phase 2: 8 chunks, B direct from L2 wh, register prefetch
  const int wrow = wave * 16 + lr;  // row within chunk
  half8 bcur[4];
#pragma unroll
  for (int s = 0; s < 4; ++s)
    bcur[s] = *(const half8*)&wh[wrow * 128 + s * 32 + quad * 8];

  for (int c = 0; c < 8; ++c) {
    half8 bnxt[4];
    if (c + 1 < 8) {
#pragma unroll
      for (int s = 0; s < 4; ++s)
        bnxt[s] = *(const half8*)&wh[((c + 1) * 128 + wrow) * 128 + s * 32 +
                                     quad * 8];
    }

    f32x4 acc2[7];
#pragma unroll
    for (int m = 0; m < 7; ++m) acc2[m] = (f32x4)(0.f);
#pragma unroll
    for (int s = 0; s < 4; ++s)
#pragma unroll
      for (int m = 0; m < 7; ++m)
        acc2[m] = __builtin_amdgcn_mfma_f32_16x16x32_f16(afr[s][m], bcur[s],
                                                         acc2[m], 0, 0, 0);

    {
      int col = c * 128 + wrow;
      float bv = bias[col];
      float pmax = -1e30f, pmin = 1e30f, psum = 0.f, psq = 0.f;
#pragma unroll
      for (int m = 0; m < 7; ++m)
#pragma unroll
        for (int r = 0; r < 4; ++r) {
          int row = m * 16 + quad * 4 + r;
          if (row < 100) {
            float y = fmaxf(acc2[m][r] + bv, 0.f);
            pmax = fmaxf(pmax, y);
            pmin = fminf(pmin, y);
            psum += y;
            psq += y * y;
          }
        }
      pmax = fmaxf(pmax, __shfl_xor(pmax, 16));
      pmax = fmaxf(pmax, __shfl_xor(pmax, 32));
      pmin = fminf(pmin, __shfl_xor(pmin, 16));
      pmin = fminf(pmin, __shfl_xor(pmin, 32));
      psum += __shfl_xor(psum, 16);
      psum += __shfl_xor(psum, 32);
      psq += __shfl_xor(psq, 16);
      psq += __shfl_xor(psq, 32);
      if (quad == 0) {
        featmax[b * C2 + col] = pmax;
        featmin[b * C2 + col] = pmin;
        featsum[b * C2 + col] = psum;
        featsq[b * C2 + col] = psq;
      }
    }
#pragma unroll
    for (int s = 0; s < 4; ++s) bcur[s] = bnxt[s];
  }
}

// ----------------- stats1: reduce per-b partials into bnsum/bnsq
__global__ __launch_bounds__(256) void stats1_kernel(
    const float* __restrict__ featsum, const float* __restrict__ featsq,
    float* __restrict__ bnsum, float* __restrict__ bnsq) {
  int col = blockIdx.x * 256 + threadIdx.x;
  int r0 = blockIdx.y * 50;
  float s = 0.f, q = 0.f;
  for (int r = r0; r < r0 + 50; ++r) {
    s += featsum[r * C2 + col];
    q += featsq[r * C2 + col];
  }
  atomicAdd(&bnsum[col], s);
  atomicAdd(&bnsq[col], q);
}

// --------------------------- BN1 finalize -> feat1 as f16 hi/lo pair
__global__ __launch_bounds__(256) void bn1half_kernel(
    const float* __restrict__ featmax, const float* __restrict__ featmin,
    const float* __restrict__ bnsum, const float* __restrict__ bnsq,
    const float* __restrict__ g, const float* __restrict__ bb,
    __half* __restrict__ Xhi, __half* __restrict__ Xlo) {
  int idx = blockIdx.x * 256 + threadIdx.x;
  if (idx >= NB * C2) return;
  int o = idx & (C2 - 1);
  const float invn = 1.f / (float)(NB * KNN);
  float m = bnsum[o] * invn;
  float v = bnsq[o] * invn - m * m;
  float a = g[o] / sqrtf(v + 1e-5f);
  float x = (a >= 0.f) ? featmax[idx] : featmin[idx];  // max of monotone map
  float y = (x - m) * a + bb[o];
  __half hi = __float2half_rn(y);
  Xhi[idx] = hi;
  Xlo[idx] = __float2half_rn(y - __half2float(hi));
}

// --------------------------- fc1 via MFMA (hi/lo X and W, 3 passes)
__global__ __launch_bounds__(256) void fc1_mfma_kernel(
    const __half* __restrict__ Xhi, const __half* __restrict__ Xlo,
    const __half* __restrict__ Whi, const __half* __restrict__ Wlo,
    const float* __restrict__ bias, float* __restrict__ yraw,
    float* __restrict__ s, float* __restrict__ sq) {
  const int r0 = blockIdx.x * 64;
  const int n0 = blockIdx.y * 64;
  const int tid = threadIdx.x;
  const int wave = tid >> 6, lane = tid & 63;
  const int lr = lane & 15, quad = lane >> 4;
  __shared__ __half Xs_hi[64 * 72], Xs_lo[64 * 72];
  __shared__ __half Ws_hi[64 * 72], Ws_lo[64 * 72];

  f32x4 acc[4];
#pragma unroll
  for (int m = 0; m < 4; ++m) acc[m] = (f32x4)(0.f);

  for (int kc = 0; kc < C2; kc += 64) {
    __syncthreads();  // protect prior-iteration reads
    for (int i = tid; i < 64 * 8; i += 256) {
      int row = i >> 3, seg = i & 7;
      int gr = r0 + row;
      float4 vhi = make_float4(0.f, 0.f, 0.f, 0.f), vlo = vhi;
      if (gr < NB) {
        vhi = *(const float4*)&Xhi[gr * C2 + kc + seg * 8];
        vlo = *(const float4*)&Xlo[gr * C2 + kc + seg * 8];
      }
      *(float4*)&Xs_hi[row * 72 + seg * 8] = vhi;
      *(float4*)&Xs_lo[row * 72 + seg * 8] = vlo;
      *(float4*)&Ws_hi[row * 72 + seg * 8] =
          *(const float4*)&Whi[(n0 + row) * C2 + kc + seg * 8];
      *(float4*)&Ws_lo[row * 72 + seg * 8] =
          *(const float4*)&Wlo[(n0 + row) * C2 + kc + seg * 8];
    }
    __syncthreads();

#pragma unroll
    for (int s2 = 0; s2 < 2; ++s2) {
      int boff = (wave * 16 + lr) * 72 + s2 * 32 + quad * 8;
      half8 bhi = *(const half8*)&Ws_hi[boff];
      half8 blo = *(const half8*)&Ws_lo[boff];
#pragma unroll
      for (int m = 0; m < 4; ++m) {
        int aoff = (m * 16 + lr) * 72 + s2 * 32 + quad * 8;
        half8 ahi = *(const half8*)&Xs_hi[aoff];
        half8 alo = *(const half8*)&Xs_lo[aoff];
        acc[m] = __builtin_amdgcn_mfma_f32_16x16x32_f16(ahi, bhi, acc[m], 0, 0, 0);
        acc[m] = __builtin_amdgcn_mfma_f32_16x16x32_f16(ahi, blo, acc[m], 0, 0, 0);
        acc[m] = __builtin_amdgcn_mfma_f32_16x16x32_f16(alo, bhi, acc[m], 0, 0, 0);
      }
    }
  }

  // epilogue: relu + write + stats
  {
    int col = n0 + wave * 16 + lr;
    float bv = bias[col];
    float psum = 0.f, psq = 0.f;
#pragma unroll
    for (int m = 0; m < 4; ++m)
#pragma unroll
      for (int r = 0; r < 4; ++r) {
        int row = r0 + m * 16 + quad * 4 + r;
        if (row < NB) {
          float y = fmaxf(acc[m][r] + bv, 0.f);
          yraw[row * C3 + col] = y;
          psum += y;
          psq += y * y;
        }
      }
    psum += __shfl_xor(psum, 16);
    psum += __shfl_xor(psum, 32);
    psq += __shfl_xor(psq, 16);
    psq += __shfl_xor(psq, 32);
    if (quad == 0) {
      atomicAdd(&s[col], psum);
      atomicAdd(&sq[col], psq);
    }
  }
}

// ----------------- fc2 via MFMA (BN4 applied in staging, hi/lo split)
__global__ __launch_bounds__(256) void fc2_mfma_kernel(
    const float* __restrict__ x,  // f2raw [500][512]
    const float* __restrict__ bnsum4, const float* __restrict__ bnsq4,
    const float* __restrict__ g, const float* __restrict__ bb,
    const __half* __restrict__ Whi, const __half* __restrict__ Wlo,
    const float* __restrict__ bias, float* __restrict__ yraw,
    float* __restrict__ s, float* __restrict__ sq) {
  const int r0 = blockIdx.x * 64;
  const int n0 = blockIdx.y * 64;
  const int tid = threadIdx.x;
  const int wave = tid >> 6, lane = tid & 63;
  const int lr = lane & 15, quad = lane >> 4;
  __shared__ __half Xs_hi[64 * 72], Xs_lo[64 * 72];
  __shared__ __half Ws_hi[64 * 72], Ws_lo[64 * 72];
  __shared__ float amul[C3], badd[C3];

  {
    const float invn = 1.f / (float)NB;
    for (int o = tid; o < C3; o += 256) {
      float m = bnsum4[o] * invn;
      float v = bnsq4[o] * invn - m * m;
      float a = g[o] / sqrtf(v + 1e-5f);
      amul[o] = a;
      badd[o] = bb[o] - m * a;
    }
  }

  f32x4 acc[4];
#pragma unroll
  for (int m = 0; m < 4; ++m) acc[m] = (f32x4)(0.f);

  for (int kc = 0; kc < C3; kc += 64) {
    __syncthreads();  // amul ready (first iter) / prior reads done
    for (int i = tid; i < 64 * 8; i += 256) {
      int row = i >> 3, seg = i & 7;
      int gr = r0 + row;
      __half hbuf[8], lbuf[8];
      if (gr < NB) {
        float4 a0 = *(const float4*)&x[gr * C3 + kc + seg * 8];
        float4 a1 = *(const float4*)&x[gr * C3 + kc + seg * 8 + 4];
        float vals[8] = {a0.x, a0.y, a0.z, a0.w, a1.x, a1.y, a1.z, a1.w};
#pragma unroll
        for (int j = 0; j < 8; ++j) {
          int o = kc + seg * 8 + j;
          float y = vals[j] * amul[o] + badd[o];
          __half hi = __float2half_rn(y);
          hbuf[j] = hi;
          lbuf[j] = __float2half_rn(y - __half2float(hi));
        }
      } else {
#pragma unroll
        for (int j = 0; j < 8; ++j) {
          hbuf[j] = __float2half_rn(0.f);
          lbuf[j] = __float2half_rn(0.f);
        }
      }
      *(float4*)&Xs_hi[row * 72 + seg * 8] = *(float4*)hbuf;
      *(float4*)&Xs_lo[row * 72 + seg * 8] = *(float4*)lbuf;
      *(float4*)&Ws_hi[row * 72 + seg * 8] =
          *(const float4*)&Whi[(n0 + row) * C3 + kc + seg * 8];
      *(float4*)&Ws_lo[row * 72 + seg * 8] =
          *(const float4*)&Wlo[(n0 + row) * C3 + kc + seg * 8];
    }
    __syncthreads();

#pragma unroll
    for (int s2 = 0; s2 < 2; ++s2) {
      int boff = (wave * 16 + lr) * 72 + s2 * 32 + quad * 8;
      half8 bhi = *(const half8*)&Ws_hi[boff];
      half8 blo = *(const half8*)&Ws_lo[boff];
#pragma unroll
      for (int m = 0; m < 4; ++m) {
        int aoff = (m * 16 + lr) * 72 + s2 * 32 + quad * 8;
        half8 ahi = *(const half8*)&Xs_hi[aoff];
        half8 alo = *(const half8*)&Xs_lo[aoff];
        acc[m] = __builtin_amdgcn_mfma_f32_16x16x32_f16(ahi, bhi, acc[m], 0, 0, 0);
        acc[m] = __builtin_amdgcn_mfma_f32_16x16x32_f16(ahi, blo, acc[m], 0, 0, 0);
        acc[m] = __builtin_amdgcn_mfma_f32_16x16x32_f16(alo, bhi, acc[m], 0, 0, 0);
      }
    }
  }

  // epilogue: relu + write + stats
  {
    int col = n0 + wave * 16 + lr;
    float bv = bias[col];
    float psum = 0.f, psq = 0.f;
#pragma unroll
    for (int m = 0; m < 4; ++m)
#pragma unroll
      for (int r = 0; r < 4; ++r) {
        int row = r0 + m * 16 + quad * 4 + r;
        if (row < NB) {
          float y = fmaxf(acc[m][r] + bv, 0.f);
          yraw[row * C4 + col] = y;
          psum += y;
          psq += y * y;
        }
      }
    psum += __shfl_xor(psum, 16);
    psum += __shfl_xor(psum, 32);
    psq += __shfl_xor(psq, 16);
    psq += __shfl_xor(psq, 32);
    if (quad == 0) {
      atomicAdd(&s[col], psum);
      atomicAdd(&sq[col], psq);
    }
  }
}

// ------------------------------------------------- fc3 (BN5 fused)
__global__ __launch_bounds__(256) void fc3_kernel(
    const float* __restrict__ x,  // f3raw [500][256]
    const float* __restrict__ bnsum, const float* __restrict__ bnsq,
    const float* __restrict__ g, const float* __restrict__ bb,
    const float* __restrict__ w, const float* __restrict__ bias,
    float* __restrict__ out) {
  const int tid = threadIdx.x;
  __shared__ float pmul[C4], padd[C4];
  {
    const float invn = 1.f / (float)NB;
    float m = bnsum[tid] * invn;
    float v = bnsq[tid] * invn - m * m;
    float a = g[tid] / sqrtf(v + 1e-5f);
    pmul[tid] = a;
    padd[tid] = bb[tid] - m * a;
  }
  __syncthreads();
  int idx = blockIdx.x * 256 + tid;
  if (idx >= NB * 3) return;
  int b = idx / 3, o = idx % 3;
  float acc = 0.f;
  for (int k = 0; k < C4; ++k)
    acc += (x[b * C4 + k] * pmul[k] + padd[k]) * w[o * C4 + k];
  out[idx] = acc + bias[o];
}

// ---------------------------------------------------------------- launch
extern "C" void kernel_launch(void* const* d_in, const int* in_sizes, int n_in,
                              void* d_out, int out_size, void* d_ws,
                              size_t ws_size, hipStream_t stream) {
  const float* pts = (const float*)d_in[0];
  const float* normal = (const float*)d_in[1];
  const float* kp_points = (const float*)d_in[2];
  const float* kp_weights = (const float*)d_in[3];
  const float* kp_sigma = (const float*)d_in[4];
  const float* conv1_w = (const float*)d_in[5];
  const float* conv1_b = (const float*)d_in[6];
  const float* bn1_g = (const float*)d_in[7];
  const float* bn1_b = (const float*)d_in[8];
  const float* fc1_w = (const float*)d_in[9];
  const float* fc1_b = (const float*)d_in[10];
  const float* bn4_g = (const float*)d_in[11];
  const float* bn4_b = (const float*)d_in[12];
  const float* fc2_w = (const float*)d_in[13];
  const float* fc2_b = (const float*)d_in[14];
  const float* bn5_g = (const float*)d_in[15];
  const float* bn5_b = (const float*)d_in[16];
  const float* fc3_w = (const float*)d_in[17];
  const float* fc3_b = (const float*)d_in[18];
  const int* index = (const int*)d_in[19];
  float* out = (float*)d_out;

  char* p = (char*)d_ws;
  auto carve = [&](size_t bytes) {
    void* r = (void*)p;
    p += (bytes + 255) & ~(size_t)255;
    return r;
  };
  float* sel = (float*)carve(NB * 3 * 4);
  int* nbr = (int*)carve(NB * KNN * 4);
  __half* wh = (__half*)carve((size_t)C2 * C1 * 2);
  __half* kpwT_hi = (__half*)carve((size_t)128 * 64 * 2);
  __half* kpwT_lo = (__half*)carve((size_t)128 * 64 * 2);
  __half* fwhi = (__half*)carve((size_t)C3 * C2 * 2);
  __half* fwlo = (__half*)carve((size_t)C3 * C2 * 2);
  __half* f2whi = (__half*)carve((size_t)C4 * C3 * 2);
  __half* f2wlo = (__half*)carve((size_t)C4 * C3 * 2);
  __half* Xhi = (__half*)carve((size_t)NB * C2 * 2);
  __half* Xlo = (__half*)carve((size_t)NB * C2 * 2);
  float* featmax = (float*)carve(NB * C2 * 4);
  float* featmin = (float*)carve(NB * C2 * 4);
  float* featsum = (float*)carve(NB * C2 * 4);
  float* featsq = (float*)carve(NB * C2 * 4);
  float* f2raw = (float*)carve(NB * C3 * 4);
  float* f3raw = (float*)carve(NB * C4 * 4);
  // stats block + gbase live in one memset region
  float* stats = (float*)carve((2 * C2 + 2 * C3 + 2 * C4 + 64) * 4);
  float* bnsum = stats;
  float* bnsq = stats + C2;
  float* s4 = stats + 2 * C2;
  float* sq4 = s4 + C3;
  float* s5 = sq4 + C3;
  float* sq5 = s5 + C4;
  unsigned* gbase = (unsigned*)(stats + 2 * C2 + 2 * C3 + 2 * C4);
  // grid structures
  unsigned* cellcnt = (unsigned*)carve((size_t)NCELLS * 4);
  unsigned* cellcur = (unsigned*)carve((size_t)NCELLS * 4);
  float4* sortedpts = (float4*)carve((size_t)NPTS * 16);

  hipMemsetAsync(stats, 0, (2 * C2 + 2 * C3 + 2 * C4 + 64) * 4, stream);
  hipMemsetAsync(cellcnt, 0, (size_t)NCELLS * 4, stream);

  prep_kernel<<<(C3 * C2 + 255) / 256, 256, 0, stream>>>(
      pts, normal, index, conv1_w, kp_weights, fc1_w, fc2_w, sel,
      out + NB * 3, wh, kpwT_hi, kpwT_lo, fwhi, fwlo, f2whi, f2wlo, cellcnt);
  grid_scan_kernel<<<256, 256, 0, stream>>>(cellcnt, cellcur, gbase);
  grid_scatter_kernel<<<(NPTS + 255) / 256, 256, 0, stream>>>(pts, cellcur,
                                                              sortedpts);
  knn_kernel<<<NB, 256, 0, stream>>>(sortedpts, cellcnt, cellcur, sel, nbr);
  kpconv_conv1_kernel<<<NB, 512, 0, stream>>>(
      pts, sel, nbr, kp_points, kpwT_hi, kpwT_lo, kp_sigma, wh, conv1_b,
      featmax, featmin, featsum, featsq);
  stats1_kernel<<<dim3(4, 10), 256, 0, stream>>>(featsum, featsq, bnsum,
                                                 bnsq);
  bn1half_kernel<<<(NB * C2 + 255) / 256, 256, 0, stream>>>(
      featmax, featmin, bnsum, bnsq, bn1_g, bn1_b, Xhi, Xlo);
  fc1_mfma_kernel<<<dim3(8, 8), 256, 0, stream>>>(Xhi, Xlo, fwhi, fwlo, fc1_b,
                                                  f2raw, s4, sq4);
  fc2_mfma_kernel<<<dim3(8, 4), 256, 0, stream>>>(
      f2raw, s4, sq4, bn4_g, bn4_b, f2whi, f2wlo, fc2_b, f3raw, s5, sq5);
  fc3_kernel<<<(NB * 3 + 255) / 256, 256, 0, stream>>>(
      f3raw, s5, sq5, bn5_g, bn5_b, fc3_w, fc3_b, out);
}

// Round 11
// 259.854 us; speedup vs baseline: 1.4115x; 1.4115x over previous
//
#include <hip/hip_runtime.h>
#include <hip/hip_fp16.h>

#define NPTS 100000
#define NB 500
#define KNN 100
#define KPN 15
#define C1 128
#define C2 1024
#define C3 512
#define C4 256

// ---- L-inf kNN grid parameters
#define G 64
#define NCELLS (G * G * G)
#define GB 5.0f
#define GINVH ((float)G / (2.f * GB))  // 6.4 cells per unit
#define CAND_CAP 2048

typedef _Float16 half8 __attribute__((ext_vector_type(8)));
typedef float f32x4 __attribute__((ext_vector_type(4)));

// ------------------------------------------------- grid helpers
__device__ __forceinline__ int cell_coord(float x) {
  int c = (int)floorf((x + GB) * GINVH);
  return min(max(c, 0), G - 1);
}
__device__ __forceinline__ int cell_of(float x, float y, float z) {
  return (cell_coord(x) << 12) | (cell_coord(y) << 6) | cell_coord(z);
}

// ------ prep: gather + converts (conv1/kpw/fc1w/fc2w hi-lo) + grid hist
__global__ __launch_bounds__(256) void prep_kernel(
    const float* __restrict__ pts, const float* __restrict__ normal,
    const int* __restrict__ index, const float* __restrict__ w1,
    const float* __restrict__ kpw, const float* __restrict__ fc1w,
    const float* __restrict__ fc2w, float* __restrict__ sel,
    float* __restrict__ out2, __half* __restrict__ wh,
    __half* __restrict__ kpwT_hi, __half* __restrict__ kpwT_lo,
    __half* __restrict__ fwhi, __half* __restrict__ fwlo,
    __half* __restrict__ f2whi, __half* __restrict__ f2wlo,
    unsigned* __restrict__ cnt) {
  int i = blockIdx.x * 256 + threadIdx.x;
  if (i < NB) {
    int ix = index[i];
    sel[i * 3 + 0] = pts[3 * ix + 0];
    sel[i * 3 + 1] = pts[3 * ix + 1];
    sel[i * 3 + 2] = pts[3 * ix + 2];
    out2[i * 3 + 0] = normal[3 * ix + 0];
    out2[i * 3 + 1] = normal[3 * ix + 1];
    out2[i * 3 + 2] = normal[3 * ix + 2];
  }
  if (i < C2 * C1) wh[i] = __float2half(w1[i]);
  if (i < 128 * 64) {
    int o = i >> 6, j = i & 63;
    float v = (j < 45) ? kpw[j * 128 + o] : 0.f;
    __half hi = __float2half_rn(v);
    kpwT_hi[i] = hi;
    kpwT_lo[i] = __float2half_rn(v - __half2float(hi));
  }
  if (i < C3 * C2) {
    float v = fc1w[i];
    __half hi = __float2half_rn(v);
    fwhi[i] = hi;
    fwlo[i] = __float2half_rn(v - __half2float(hi));
  }
  if (i < C4 * C3) {
    float v = fc2w[i];
    __half hi = __float2half_rn(v);
    f2whi[i] = hi;
    f2wlo[i] = __float2half_rn(v - __half2float(hi));
  }
  if (i < NPTS)
    atomicAdd(&cnt[cell_of(pts[3 * i], pts[3 * i + 1], pts[3 * i + 2])], 1u);
}

// --------------- grid scan: single kernel, atomic chunk-base assignment
__global__ __launch_bounds__(256) void grid_scan_kernel(
    const unsigned* __restrict__ cnt, unsigned* __restrict__ cursor,
    unsigned* __restrict__ gbase) {
  const int tid = threadIdx.x;
  int base = blockIdx.x * 1024 + tid * 4;
  unsigned c0 = cnt[base], c1 = cnt[base + 1], c2 = cnt[base + 2],
           c3 = cnt[base + 3];
  unsigned tot = c0 + c1 + c2 + c3;
  __shared__ unsigned sb[256];
  __shared__ unsigned s_base;
  sb[tid] = tot;
  __syncthreads();
  for (int off = 1; off < 256; off <<= 1) {
    unsigned add = (tid >= off) ? sb[tid - off] : 0u;
    __syncthreads();
    sb[tid] += add;
    __syncthreads();
  }
  if (tid == 255) s_base = atomicAdd(gbase, sb[255]);
  __syncthreads();
  unsigned excl = s_base + sb[tid] - tot;
  cursor[base] = excl;
  cursor[base + 1] = excl + c0;
  cursor[base + 2] = excl + c0 + c1;
  cursor[base + 3] = excl + c0 + c1 + c2;
}

// scatter: cursor turns into per-cell END offsets; begin = end - cnt
__global__ __launch_bounds__(256) void grid_scatter_kernel(
    const float* __restrict__ pts, unsigned* __restrict__ cursor,
    float4* __restrict__ sorted) {
  int i = blockIdx.x * 256 + threadIdx.x;
  if (i >= NPTS) return;
  float x = pts[3 * i], y = pts[3 * i + 1], z = pts[3 * i + 2];
  unsigned pos = atomicAdd(&cursor[cell_of(x, y, z)], 1u);
  sorted[pos] = make_float4(x, y, z, __int_as_float(i));
}

// ---------------------------------------------------------------- kNN v8
// v8 fixes v7's regression: the nested-cube Phase-C skip is kept, but the
// Phase-B candidate set is COMPACTED in LDS (bits < bub) before the
// O(mc^2) rank-select. v7 ran rank-select over the full set (m up to
// thousands in dense regions -> 145us). Two-phase compaction (register
// buffer, barrier, write-back) avoids read/write races.
__device__ __forceinline__ unsigned linf_bits(float px, float py, float pz,
                                              float sx, float sy, float sz) {
  float dx = fabsf(px - sx), dy = fabsf(py - sy), dz = fabsf(pz - sz);
  return __float_as_uint(fmaxf(fmaxf(dx, dy), dz));
}

__global__ __launch_bounds__(256) void knn_kernel(
    const float4* __restrict__ sorted, const unsigned* __restrict__ cnt,
    const unsigned* __restrict__ cursor,  // per-cell end offsets
    const float* __restrict__ sel, int* __restrict__ nbr) {
  const int b = blockIdx.x;
  const int tid = threadIdx.x;
  __shared__ unsigned cbits[CAND_CAP];
  __shared__ int cidx[CAND_CAP];
  __shared__ unsigned hist[4096];
  __shared__ unsigned scanbuf[256];
  __shared__ int s_total, s_m, s_mc, s_chunk;
  __shared__ unsigned s_excl, s_bub;

  const float qx = sel[b * 3 + 0], qy = sel[b * 3 + 1], qz = sel[b * 3 + 2];
  const int qcx = cell_coord(qx), qcy = cell_coord(qy), qcz = cell_coord(qz);

  // ---------------- Phase A: expand cube until >=KNN (shell-incremental)
  if (tid == 0) s_total = 0;
  __syncthreads();
  int s = 1;
  int pxlo = 1, pxhi = 0, pylo = 1, pyhi = 0, pzlo = 1, pzhi = 0;  // empty
  int xlo, xhi, ylo, yhi, zlo, zhi;
  for (;;) {
    xlo = max(qcx - s, 0); xhi = min(qcx + s, G - 1);
    ylo = max(qcy - s, 0); yhi = min(qcy + s, G - 1);
    zlo = max(qcz - s, 0); zhi = min(qcz + s, G - 1);
    int nx = xhi - xlo + 1, ny = yhi - ylo + 1, nz = zhi - zlo + 1;
    int ncell = nx * ny * nz;
    unsigned local = 0;
    for (int ci = tid; ci < ncell; ci += 256) {
      int cz = ci % nz;
      int r = ci / nz;
      int cy = r % ny;
      int cx = r / ny;
      int ax = xlo + cx, ay = ylo + cy, az = zlo + cz;
      if (ax >= pxlo && ax <= pxhi && ay >= pylo && ay <= pyhi &&
          az >= pzlo && az <= pzhi)
        continue;  // interior (already counted)
      local += cnt[(ax << 12) | (ay << 6) | az];
    }
#pragma unroll
    for (int off = 32; off; off >>= 1) local += __shfl_down(local, off);
    if ((tid & 63) == 0) atomicAdd(&s_total, (int)local);
    __syncthreads();
    if (s_total >= KNN || (xlo == 0 && ylo == 0 && zlo == 0 && xhi == G - 1 &&
                           yhi == G - 1 && zhi == G - 1))
      break;
    pxlo = xlo; pxhi = xhi; pylo = ylo; pyhi = yhi; pzlo = zlo; pzhi = zhi;
    ++s;
    __syncthreads();
  }

  // ---------------- Phase B: collect cube points (per-cell batched slots)
  if (tid == 0) s_m = 0;
  __syncthreads();
  {
    int nx = xhi - xlo + 1, ny = yhi - ylo + 1, nz = zhi - zlo + 1;
    int ncell = nx * ny * nz;
    for (int ci = tid; ci < ncell; ci += 256) {
      int cz = ci % nz;
      int r = ci / nz;
      int cy = r % ny;
      int cx = r / ny;
      int cell = ((xlo + cx) << 12) | ((ylo + cy) << 6) | (zlo + cz);
      unsigned end = cursor[cell];
      unsigned beg = end - cnt[cell];
      int k = (int)(end - beg);
      if (k > 0) {
        int e0 = atomicAdd(&s_m, k);
        for (unsigned p = beg; p < end; ++p, ++e0) {
          if (e0 < CAND_CAP) {
            float4 f = sorted[p];
            cbits[e0] = linf_bits(f.x, f.y, f.z, qx, qy, qz);
            cidx[e0] = __float_as_int(f.w);
          }
        }
      }
    }
  }
  __syncthreads();
  int m = s_m < CAND_CAP ? s_m : CAND_CAP;

  // ---------------- histogram select: upper bound on 100th distance
  for (int j = tid; j < 4096; j += 256) hist[j] = 0;
  __syncthreads();
  for (int e = tid; e < m; e += 256) atomicAdd(&hist[cbits[e] >> 19], 1u);
  __syncthreads();
  unsigned csum = 0;
  {
    int c0 = tid * 16;
#pragma unroll
    for (int j = 0; j < 16; ++j) csum += hist[c0 + j];
  }
  scanbuf[tid] = csum;
  __syncthreads();
  for (int off = 1; off < 256; off <<= 1) {
    unsigned add = (tid >= off) ? scanbuf[tid - off] : 0u;
    __syncthreads();
    scanbuf[tid] += add;
    __syncthreads();
  }
  {
    unsigned incl = scanbuf[tid], excl = incl - csum;
    if (excl < KNN && KNN <= incl) {
      s_chunk = tid;
      s_excl = excl;
    }
  }
  __syncthreads();
  if (tid == 0) {
    unsigned cum = s_excl;
    int bin = s_chunk * 16;
    while (cum + hist[bin] < KNN) {
      cum += hist[bin];
      ++bin;
    }
    s_bub = (unsigned)(bin + 1) << 19;  // exclusive upper bound on bits
  }
  __syncthreads();

  // ---------------- Phase C: filter to bits < bub
  const unsigned bub = s_bub;
  const float dub = __uint_as_float(bub);
  int xlo2 = min(max((int)floorf((qx - dub + GB) * GINVH), 0), G - 1);
  int xhi2 = min(max((int)floorf((qx + dub + GB) * GINVH), 0), G - 1);
  int ylo2 = min(max((int)floorf((qy - dub + GB) * GINVH), 0), G - 1);
  int yhi2 = min(max((int)floorf((qy + dub + GB) * GINVH), 0), G - 1);
  int zlo2 = min(max((int)floorf((qz - dub + GB) * GINVH), 0), G - 1);
  int zhi2 = min(max((int)floorf((qz + dub + GB) * GINVH), 0), G - 1);
  const bool nested = (s_m <= CAND_CAP) && xlo2 >= xlo && xhi2 <= xhi &&
                      ylo2 >= ylo && yhi2 <= yhi && zlo2 >= zlo && zhi2 <= zhi;

  int mc;
  if (nested) {
    // Phase-B set is a superset of all points with bits < bub; compact it
    // in place (two-phase: register-buffer reads, barrier, write back).
    if (tid == 0) s_mc = 0;
    __syncthreads();
    unsigned kb[8];
    int ki[8];
    int nloc = 0;
    for (int c = tid; c < m; c += 256) {  // slice <= ceil(2048/256) = 8
      unsigned bc = cbits[c];
      if (bc < bub) {
        kb[nloc] = bc;
        ki[nloc] = cidx[c];
        ++nloc;
      }
    }
    int base = 0;
    if (nloc) base = atomicAdd(&s_mc, nloc);
    __syncthreads();  // all reads complete before overwrites
    for (int j = 0; j < nloc; ++j) {
      cbits[base + j] = kb[j];
      cidx[base + j] = ki[j];
    }
    __syncthreads();
    mc = s_mc;  // <= m <= CAND_CAP
  } else {
    if (tid == 0) s_mc = 0;
    __syncthreads();
    {
      int nx = xhi2 - xlo2 + 1, ny = yhi2 - ylo2 + 1, nz = zhi2 - zlo2 + 1;
      int ncell = nx * ny * nz;
      for (int ci = tid; ci < ncell; ci += 256) {
        int cz = ci % nz;
        int r = ci / nz;
        int cy = r % ny;
        int cx = r / ny;
        int cell = ((xlo2 + cx) << 12) | ((ylo2 + cy) << 6) | (zlo2 + cz);
        unsigned end = cursor[cell];
        unsigned beg = end - cnt[cell];
        for (unsigned p = beg; p < end; ++p) {
          float4 f = sorted[p];
          unsigned bits = linf_bits(f.x, f.y, f.z, qx, qy, qz);
          if (bits < bub) {
            int e = atomicAdd(&s_mc, 1);
            if (e < CAND_CAP) {
              cbits[e] = bits;
              cidx[e] = __float_as_int(f.w);
            }
          }
        }
      }
    }
    __syncthreads();
    mc = s_mc < CAND_CAP ? s_mc : CAND_CAP;
  }

  // ---------------- exact rank-select (ties by original index, stable)
  for (int c = tid; c < mc; c += 256) {
    unsigned bc = cbits[c];
    int ic = cidx[c];
    int rank = 0;
    for (int j = 0; j < mc; ++j) {
      unsigned bj = cbits[j];
      rank += (bj < bc || (bj == bc && cidx[j] < ic)) ? 1 : 0;
    }
    if (rank < KNN) nbr[b * KNN + rank] = ic;
  }
}

// ---------------------------- KPConv + conv1 FUSED (f16 MFMA, 8 waves)
// v4: per-(b,col) stats stored once (no 500-way atomic contention);
// stats1_kernel reduces. Phase-2 LDS-free (A-frags in regs, B from L2).
__global__ __launch_bounds__(512, 2) void kpconv_conv1_kernel(
    const float* __restrict__ pts, const float* __restrict__ sel,
    const int* __restrict__ nbr, const float* __restrict__ kp_points,
    const __half* __restrict__ kpwT_hi, const __half* __restrict__ kpwT_lo,
    const float* __restrict__ kp_sigma, const __half* __restrict__ wh,
    const float* __restrict__ bias, float* __restrict__ featmax,
    float* __restrict__ featmin, float* __restrict__ featsum,
    float* __restrict__ featsq) {
  const int b = blockIdx.x;
  const int tid = threadIdx.x;
  const int wave = tid >> 6, lane = tid & 63;
  const int lr = lane & 15, quad = lane >> 4;

  __shared__ __align__(16) char smem[71168];
  // phase-1 carve
  __half* As_hi = (__half*)smem;            // 112*72
  __half* As_lo = As_hi + 112 * 72;
  __half* Bs_hi = As_lo + 112 * 72;         // 128*72
  __half* Bs_lo = Bs_hi + 128 * 72;
  float* rel = (float*)(Bs_lo + 128 * 72);  // 100*4
  float* kpp = rel + 100 * 4;               // 48
  // phase-2 overlay: Hs only
  __half* Hs = (__half*)smem;               // 112*136

  // ---- phase 1 staging
  for (int i = tid; i < 128 * 8; i += 512) {
    int row = i >> 3, seg = i & 7;
    *(float4*)&Bs_hi[row * 72 + seg * 8] =
        *(const float4*)&kpwT_hi[row * 64 + seg * 8];
    *(float4*)&Bs_lo[row * 72 + seg * 8] =
        *(const float4*)&kpwT_lo[row * 64 + seg * 8];
  }
  {
    float4 z = make_float4(0.f, 0.f, 0.f, 0.f);
    for (int i = tid; i < 112 * 8; i += 512) {
      int row = i >> 3, seg = i & 7;
      *(float4*)&As_hi[row * 72 + seg * 8] = z;
      *(float4*)&As_lo[row * 72 + seg * 8] = z;
    }
  }
  if (tid < 45) kpp[tid] = kp_points[tid];
  if (tid < 100) {
    int idx = nbr[b * KNN + tid];
    rel[tid * 4 + 0] = pts[3 * idx + 0] - sel[b * 3 + 0];
    rel[tid * 4 + 1] = pts[3 * idx + 1] - sel[b * 3 + 1];
    rel[tid * 4 + 2] = pts[3 * idx + 2] - sel[b * 3 + 2];
  }
  __syncthreads();

  const float sg = kp_sigma[0];
  const float inv2s2 = -0.5f / (sg * sg);
  for (int i = tid; i < 100 * KPN; i += 512) {
    int k = i / KPN, p = i - k * KPN;
    float rx = rel[k * 4 + 0] - kpp[p * 3 + 0];
    float ry = rel[k * 4 + 1] - kpp[p * 3 + 1];
    float rz = rel[k * 4 + 2] - kpp[p * 3 + 2];
    float w = expf(inv2s2 * (rx * rx + ry * ry + rz * rz));
#pragma unroll
    for (int c = 0; c < 3; ++c) {
      float a = rel[k * 4 + c] * w;
      __half hi = __float2half_rn(a);
      As_hi[k * 72 + p * 3 + c] = hi;
      As_lo[k * 72 + p * 3 + c] = __float2half_rn(a - __half2float(hi));
    }
  }
  __syncthreads();

  // ---- phase 1 MFMA: acc = Ahi*Bhi + Ahi*Blo + Alo*Bhi (wave owns tile w)
  f32x4 acc1[7];
#pragma unroll
  for (int m = 0; m < 7; ++m) acc1[m] = (f32x4)(0.f);
#pragma unroll
  for (int s = 0; s < 2; ++s) {
    int boff = (wave * 16 + lr) * 72 + s * 32 + quad * 8;
    half8 bhi = *(const half8*)&Bs_hi[boff];
    half8 blo = *(const half8*)&Bs_lo[boff];
#pragma unroll
    for (int m = 0; m < 7; ++m) {
      int aoff = (m * 16 + lr) * 72 + s * 32 + quad * 8;
      half8 ahi = *(const half8*)&As_hi[aoff];
      half8 alo = *(const half8*)&As_lo[aoff];
      acc1[m] = __builtin_amdgcn_mfma_f32_16x16x32_f16(ahi, bhi, acc1[m], 0, 0, 0);
      acc1[m] = __builtin_amdgcn_mfma_f32_16x16x32_f16(ahi, blo, acc1[m], 0, 0, 0);
      acc1[m] = __builtin_amdgcn_mfma_f32_16x16x32_f16(alo, bhi, acc1[m], 0, 0, 0);
    }
  }
  __syncthreads();  // As/Bs dead; safe to overlay Hs

  // ---- write h tile to LDS (rows>=100 zero: As rows were zeroed)
  {
    int col = wave * 16 + lr;
#pragma unroll
    for (int m = 0; m < 7; ++m)
#pragma unroll
      for (int r = 0; r < 4; ++r) {
        int row = m * 16 + quad * 4 + r;
        Hs[row * 136 + col] = __float2half_rn(fmaxf(acc1[m][r], 0.f));
      }
  }
  __syncthreads();  // Hs complete (cross-wave cols)

  // ---- cache all A-fragments in registers (one-time LDS read)
  half8 afr[4][7];
#pragma unroll
  for (int s = 0; s < 4; ++s)
#pragma unroll
    for (int m = 0; m < 7; ++m)
      afr[s][m] = *(const half8*)&Hs[(m * 16 + lr) * 136 + s * 32 + quad * 8];

  // ---- phase 2: 8 chunks, B direct from L2 wh, register prefetch
  const int wrow = wave * 16 + lr;  // row within chunk
  half8 bcur[4];
#pragma unroll
  for (int s = 0; s < 4; ++s)
    bcur[s] = *(const half8*)&wh[wrow * 128 + s * 32 + quad * 8];

  for (int c = 0; c < 8; ++c) {
    half8 bnxt[4];
    if (c + 1 < 8) {
#pragma unroll
      for (int s = 0; s < 4; ++s)
        bnxt[s] = *(const half8*)&wh[((c + 1) * 128 + wrow) * 128 + s * 32 +
                                     quad * 8];
    }

    f32x4 acc2[7];
#pragma unroll
    for (int m = 0; m < 7; ++m) acc2[m] = (f32x4)(0.f);
#pragma unroll
    for (int s = 0; s < 4; ++s)
#pragma unroll
      for (int m = 0; m < 7; ++m)
        acc2[m] = __builtin_amdgcn_mfma_f32_16x16x32_f16(afr[s][m], bcur[s],
                                                         acc2[m], 0, 0, 0);

    {
      int col = c * 128 + wrow;
      float bv = bias[col];
      float pmax = -1e30f, pmin = 1e30f, psum = 0.f, psq = 0.f;
#pragma unroll
      for (int m = 0; m < 7; ++m)
#pragma unroll
        for (int r = 0; r < 4; ++r) {
          int row = m * 16 + quad * 4 + r;
          if (row < 100) {
            float y = fmaxf(acc2[m][r] + bv, 0.f);
            pmax = fmaxf(pmax, y);
            pmin = fminf(pmin, y);
            psum += y;
            psq += y * y;
          }
        }
      pmax = fmaxf(pmax, __shfl_xor(pmax, 16));
      pmax = fmaxf(pmax, __shfl_xor(pmax, 32));
      pmin = fminf(pmin, __shfl_xor(pmin, 16));
      pmin = fminf(pmin, __shfl_xor(pmin, 32));
      psum += __shfl_xor(psum, 16);
      psum += __shfl_xor(psum, 32);
      psq += __shfl_xor(psq, 16);
      psq += __shfl_xor(psq, 32);
      if (quad == 0) {
        featmax[b * C2 + col] = pmax;
        featmin[b * C2 + col] = pmin;
        featsum[b * C2 + col] = psum;
        featsq[b * C2 + col] = psq;
      }
    }
#pragma unroll
    for (int s = 0; s < 4; ++s) bcur[s] = bnxt[s];
  }
}

// ----------------- stats1: reduce per-b partials into bnsum/bnsq
__global__ __launch_bounds__(256) void stats1_kernel(
    const float* __restrict__ featsum, const float* __restrict__ featsq,
    float* __restrict__ bnsum, float* __restrict__ bnsq) {
  int col = blockIdx.x * 256 + threadIdx.x;
  int r0 = blockIdx.y * 50;
  float s = 0.f, q = 0.f;
  for (int r = r0; r < r0 + 50; ++r) {
    s += featsum[r * C2 + col];
    q += featsq[r * C2 + col];
  }
  atomicAdd(&bnsum[col], s);
  atomicAdd(&bnsq[col], q);
}

// --------------------------- BN1 finalize -> feat1 as f16 hi/lo pair
__global__ __launch_bounds__(256) void bn1half_kernel(
    const float* __restrict__ featmax, const float* __restrict__ featmin,
    const float* __restrict__ bnsum, const float* __restrict__ bnsq,
    const float* __restrict__ g, const float* __restrict__ bb,
    __half* __restrict__ Xhi, __half* __restrict__ Xlo) {
  int idx = blockIdx.x * 256 + threadIdx.x;
  if (idx >= NB * C2) return;
  int o = idx & (C2 - 1);
  const float invn = 1.f / (float)(NB * KNN);
  float m = bnsum[o] * invn;
  float v = bnsq[o] * invn - m * m;
  float a = g[o] / sqrtf(v + 1e-5f);
  float x = (a >= 0.f) ? featmax[idx] : featmin[idx];  // max of monotone map
  float y = (x - m) * a + bb[o];
  __half hi = __float2half_rn(y);
  Xhi[idx] = hi;
  Xlo[idx] = __float2half_rn(y - __half2float(hi));
}

// --------------------------- fc1 via MFMA (hi/lo X and W, 3 passes)
__global__ __launch_bounds__(256) void fc1_mfma_kernel(
    const __half* __restrict__ Xhi, const __half* __restrict__ Xlo,
    const __half* __restrict__ Whi, const __half* __restrict__ Wlo,
    const float* __restrict__ bias, float* __restrict__ yraw,
    float* __restrict__ s, float* __restrict__ sq) {
  const int r0 = blockIdx.x * 64;
  const int n0 = blockIdx.y * 64;
  const int tid = threadIdx.x;
  const int wave = tid >> 6, lane = tid & 63;
  const int lr = lane & 15, quad = lane >> 4;
  __shared__ __half Xs_hi[64 * 72], Xs_lo[64 * 72];
  __shared__ __half Ws_hi[64 * 72], Ws_lo[64 * 72];

  f32x4 acc[4];
#pragma unroll
  for (int m = 0; m < 4; ++m) acc[m] = (f32x4)(0.f);

  for (int kc = 0; kc < C2; kc += 64) {
    __syncthreads();  // protect prior-iteration reads
    for (int i = tid; i < 64 * 8; i += 256) {
      int row = i >> 3, seg = i & 7;
      int gr = r0 + row;
      float4 vhi = make_float4(0.f, 0.f, 0.f, 0.f), vlo = vhi;
      if (gr < NB) {
        vhi = *(const float4*)&Xhi[gr * C2 + kc + seg * 8];
        vlo = *(const float4*)&Xlo[gr * C2 + kc + seg * 8];
      }
      *(float4*)&Xs_hi[row * 72 + seg * 8] = vhi;
      *(float4*)&Xs_lo[row * 72 + seg * 8] = vlo;
      *(float4*)&Ws_hi[row * 72 + seg * 8] =
          *(const float4*)&Whi[(n0 + row) * C2 + kc + seg * 8];
      *(float4*)&Ws_lo[row * 72 + seg * 8] =
          *(const float4*)&Wlo[(n0 + row) * C2 + kc + seg * 8];
    }
    __syncthreads();

#pragma unroll
    for (int s2 = 0; s2 < 2; ++s2) {
      int boff = (wave * 16 + lr) * 72 + s2 * 32 + quad * 8;
      half8 bhi = *(const half8*)&Ws_hi[boff];
      half8 blo = *(const half8*)&Ws_lo[boff];
#pragma unroll
      for (int m = 0; m < 4; ++m) {
        int aoff = (m * 16 + lr) * 72 + s2 * 32 + quad * 8;
        half8 ahi = *(const half8*)&Xs_hi[aoff];
        half8 alo = *(const half8*)&Xs_lo[aoff];
        acc[m] = __builtin_amdgcn_mfma_f32_16x16x32_f16(ahi, bhi, acc[m], 0, 0, 0);
        acc[m] = __builtin_amdgcn_mfma_f32_16x16x32_f16(ahi, blo, acc[m], 0, 0, 0);
        acc[m] = __builtin_amdgcn_mfma_f32_16x16x32_f16(alo, bhi, acc[m], 0, 0, 0);
      }
    }
  }

  // epilogue: relu + write + stats
  {
    int col = n0 + wave * 16 + lr;
    float bv = bias[col];
    float psum = 0.f, psq = 0.f;
#pragma unroll
    for (int m = 0; m < 4; ++m)
#pragma unroll
      for (int r = 0; r < 4; ++r) {
        int row = r0 + m * 16 + quad * 4 + r;
        if (row < NB) {
          float y = fmaxf(acc[m][r] + bv, 0.f);
          yraw[row * C3 + col] = y;
          psum += y;
          psq += y * y;
        }
      }
    psum += __shfl_xor(psum, 16);
    psum += __shfl_xor(psum, 32);
    psq += __shfl_xor(psq, 16);
    psq += __shfl_xor(psq, 32);
    if (quad == 0) {
      atomicAdd(&s[col], psum);
      atomicAdd(&sq[col], psq);
    }
  }
}

// ----------------- fc2 via MFMA (BN4 applied in staging, hi/lo split)
__global__ __launch_bounds__(256) void fc2_mfma_kernel(
    const float* __restrict__ x,  // f2raw [500][512]
    const float* __restrict__ bnsum4, const float* __restrict__ bnsq4,
    const float* __restrict__ g, const float* __restrict__ bb,
    const __half* __restrict__ Whi, const __half* __restrict__ Wlo,
    const float* __restrict__ bias, float* __restrict__ yraw,
    float* __restrict__ s, float* __restrict__ sq) {
  const int r0 = blockIdx.x * 64;
  const int n0 = blockIdx.y * 64;
  const int tid = threadIdx.x;
  const int wave = tid >> 6, lane = tid & 63;
  const int lr = lane & 15, quad = lane >> 4;
  __shared__ __half Xs_hi[64 * 72], Xs_lo[64 * 72];
  __shared__ __half Ws_hi[64 * 72], Ws_lo[64 * 72];
  __shared__ float amul[C3], badd[C3];

  {
    const float invn = 1.f / (float)NB;
    for (int o = tid; o < C3; o += 256) {
      float m = bnsum4[o] * invn;
      float v = bnsq4[o] * invn - m * m;
      float a = g[o] / sqrtf(v + 1e-5f);
      amul[o] = a;
      badd[o] = bb[o] - m * a;
    }
  }

  f32x4 acc[4];
#pragma unroll
  for (int m = 0; m < 4; ++m) acc[m] = (f32x4)(0.f);

  for (int kc = 0; kc < C3; kc += 64) {
    __syncthreads();  // amul ready (first iter) / prior reads done
    for (int i = tid; i < 64 * 8; i += 256) {
      int row = i >> 3, seg = i & 7;
      int gr = r0 + row;
      __half hbuf[8], lbuf[8];
      if (gr < NB) {
        float4 a0 = *(const float4*)&x[gr * C3 + kc + seg * 8];
        float4 a1 = *(const float4*)&x[gr * C3 + kc + seg * 8 + 4];
        float vals[8] = {a0.x, a0.y, a0.z, a0.w, a1.x, a1.y, a1.z, a1.w};
#pragma unroll
        for (int j = 0; j < 8; ++j) {
          int o = kc + seg * 8 + j;
          float y = vals[j] * amul[o] + badd[o];
          __half hi = __float2half_rn(y);
          hbuf[j] = hi;
          lbuf[j] = __float2half_rn(y - __half2float(hi));
        }
      } else {
#pragma unroll
        for (int j = 0; j < 8; ++j) {
          hbuf[j] = __float2half_rn(0.f);
          lbuf[j] = __float2half_rn(0.f);
        }
      }
      *(float4*)&Xs_hi[row * 72 + seg * 8] = *(float4*)hbuf;
      *(float4*)&Xs_lo[row * 72 + seg * 8] = *(float4*)lbuf;
      *(float4*)&Ws_hi[row * 72 + seg * 8] =
          *(const float4*)&Whi[(n0 + row) * C3 + kc + seg * 8];
      *(float4*)&Ws_lo[row * 72 + seg * 8] =
          *(const float4*)&Wlo[(n0 + row) * C3 + kc + seg * 8];
    }
    __syncthreads();

#pragma unroll
    for (int s2 = 0; s2 < 2; ++s2) {
      int boff = (wave * 16 + lr) * 72 + s2 * 32 + quad * 8;
      half8 bhi = *(const half8*)&Ws_hi[boff];
      half8 blo = *(const half8*)&Ws_lo[boff];
#pragma unroll
      for (int m = 0; m < 4; ++m) {
        int aoff = (m * 16 + lr) * 72 + s2 * 32 + quad * 8;
        half8 ahi = *(const half8*)&Xs_hi[aoff];
        half8 alo = *(const half8*)&Xs_lo[aoff];
        acc[m] = __builtin_amdgcn_mfma_f32_16x16x32_f16(ahi, bhi, acc[m], 0, 0, 0);
        acc[m] = __builtin_amdgcn_mfma_f32_16x16x32_f16(ahi, blo, acc[m], 0, 0, 0);
        acc[m] = __builtin_amdgcn_mfma_f32_16x16x32_f16(alo, bhi, acc[m], 0, 0, 0);
      }
    }
  }

  // epilogue: relu + write + stats
  {
    int col = n0 + wave * 16 + lr;
    float bv = bias[col];
    float psum = 0.f, psq = 0.f;
#pragma unroll
    for (int m = 0; m < 4; ++m)
#pragma unroll
      for (int r = 0; r < 4; ++r) {
        int row = r0 + m * 16 + quad * 4 + r;
        if (row < NB) {
          float y = fmaxf(acc[m][r] + bv, 0.f);
          yraw[row * C4 + col] = y;
          psum += y;
          psq += y * y;
        }
      }
    psum += __shfl_xor(psum, 16);
    psum += __shfl_xor(psum, 32);
    psq += __shfl_xor(psq, 16);
    psq += __shfl_xor(psq, 32);
    if (quad == 0) {
      atomicAdd(&s[col], psum);
      atomicAdd(&sq[col], psq);
    }
  }
}

// ------------------------------------------------- fc3 (BN5 fused)
__global__ __launch_bounds__(256) void fc3_kernel(
    const float* __restrict__ x,  // f3raw [500][256]
    const float* __restrict__ bnsum, const float* __restrict__ bnsq,
    const float* __restrict__ g, const float* __restrict__ bb,
    const float* __restrict__ w, const float* __restrict__ bias,
    float* __restrict__ out) {
  const int tid = threadIdx.x;
  __shared__ float pmul[C4], padd[C4];
  {
    const float invn = 1.f / (float)NB;
    float m = bnsum[tid] * invn;
    float v = bnsq[tid] * invn - m * m;
    float a = g[tid] / sqrtf(v + 1e-5f);
    pmul[tid] = a;
    padd[tid] = bb[tid] - m * a;
  }
  __syncthreads();
  int idx = blockIdx.x * 256 + tid;
  if (idx >= NB * 3) return;
  int b = idx / 3, o = idx % 3;
  float acc = 0.f;
  for (int k = 0; k < C4; ++k)
    acc += (x[b * C4 + k] * pmul[k] + padd[k]) * w[o * C4 + k];
  out[idx] = acc + bias[o];
}

// ---------------------------------------------------------------- launch
extern "C" void kernel_launch(void* const* d_in, const int* in_sizes, int n_in,
                              void* d_out, int out_size, void* d_ws,
                              size_t ws_size, hipStream_t stream) {
  const float* pts = (const float*)d_in[0];
  const float* normal = (const float*)d_in[1];
  const float* kp_points = (const float*)d_in[2];
  const float* kp_weights = (const float*)d_in[3];
  const float* kp_sigma = (const float*)d_in[4];
  const float* conv1_w = (const float*)d_in[5];
  const float* conv1_b = (const float*)d_in[6];
  const float* bn1_g = (const float*)d_in[7];
  const float* bn1_b = (const float*)d_in[8];
  const float* fc1_w = (const float*)d_in[9];
  const float* fc1_b = (const float*)d_in[10];
  const float* bn4_g = (const float*)d_in[11];
  const float* bn4_b = (const float*)d_in[12];
  const float* fc2_w = (const float*)d_in[13];
  const float* fc2_b = (const float*)d_in[14];
  const float* bn5_g = (const float*)d_in[15];
  const float* bn5_b = (const float*)d_in[16];
  const float* fc3_w = (const float*)d_in[17];
  const float* fc3_b = (const float*)d_in[18];
  const int* index = (const int*)d_in[19];
  float* out = (float*)d_out;

  char* p = (char*)d_ws;
  auto carve = [&](size_t bytes) {
    void* r = (void*)p;
    p += (bytes + 255) & ~(size_t)255;
    return r;
  };
  float* sel = (float*)carve(NB * 3 * 4);
  int* nbr = (int*)carve(NB * KNN * 4);
  __half* wh = (__half*)carve((size_t)C2 * C1 * 2);
  __half* kpwT_hi = (__half*)carve((size_t)128 * 64 * 2);
  __half* kpwT_lo = (__half*)carve((size_t)128 * 64 * 2);
  __half* fwhi = (__half*)carve((size_t)C3 * C2 * 2);
  __half* fwlo = (__half*)carve((size_t)C3 * C2 * 2);
  __half* f2whi = (__half*)carve((size_t)C4 * C3 * 2);
  __half* f2wlo = (__half*)carve((size_t)C4 * C3 * 2);
  __half* Xhi = (__half*)carve((size_t)NB * C2 * 2);
  __half* Xlo = (__half*)carve((size_t)NB * C2 * 2);
  float* featmax = (float*)carve(NB * C2 * 4);
  float* featmin = (float*)carve(NB * C2 * 4);
  float* featsum = (float*)carve(NB * C2 * 4);
  float* featsq = (float*)carve(NB * C2 * 4);
  float* f2raw = (float*)carve(NB * C3 * 4);
  float* f3raw = (float*)carve(NB * C4 * 4);
  // stats block + gbase live in one memset region
  float* stats = (float*)carve((2 * C2 + 2 * C3 + 2 * C4 + 64) * 4);
  float* bnsum = stats;
  float* bnsq = stats + C2;
  float* s4 = stats + 2 * C2;
  float* sq4 = s4 + C3;
  float* s5 = sq4 + C3;
  float* sq5 = s5 + C4;
  unsigned* gbase = (unsigned*)(stats + 2 * C2 + 2 * C3 + 2 * C4);
  // grid structures
  unsigned* cellcnt = (unsigned*)carve((size_t)NCELLS * 4);
  unsigned* cellcur = (unsigned*)carve((size_t)NCELLS * 4);
  float4* sortedpts = (float4*)carve((size_t)NPTS * 16);

  hipMemsetAsync(stats, 0, (2 * C2 + 2 * C3 + 2 * C4 + 64) * 4, stream);
  hipMemsetAsync(cellcnt, 0, (size_t)NCELLS * 4, stream);

  prep_kernel<<<(C3 * C2 + 255) / 256, 256, 0, stream>>>(
      pts, normal, index, conv1_w, kp_weights, fc1_w, fc2_w, sel,
      out + NB * 3, wh, kpwT_hi, kpwT_lo, fwhi, fwlo, f2whi, f2wlo, cellcnt);
  grid_scan_kernel<<<256, 256, 0, stream>>>(cellcnt, cellcur, gbase);
  grid_scatter_kernel<<<(NPTS + 255) / 256, 256, 0, stream>>>(pts, cellcur,
                                                              sortedpts);
  knn_kernel<<<NB, 256, 0, stream>>>(sortedpts, cellcnt, cellcur, sel, nbr);
  kpconv_conv1_kernel<<<NB, 512, 0, stream>>>(
      pts, sel, nbr, kp_points, kpwT_hi, kpwT_lo, kp_sigma, wh, conv1_b,
      featmax, featmin, featsum, featsq);
  stats1_kernel<<<dim3(4, 10), 256, 0, stream>>>(featsum, featsq, bnsum,
                                                 bnsq);
  bn1half_kernel<<<(NB * C2 + 255) / 256, 256, 0, stream>>>(
      featmax, featmin, bnsum, bnsq, bn1_g, bn1_b, Xhi, Xlo);
  fc1_mfma_kernel<<<dim3(8, 8), 256, 0, stream>>>(Xhi, Xlo, fwhi, fwlo, fc1_b,
                                                  f2raw, s4, sq4);
  fc2_mfma_kernel<<<dim3(8, 4), 256, 0, stream>>>(
      f2raw, s4, sq4, bn4_g, bn4_b, f2whi, f2wlo, fc2_b, f3raw, s5, sq5);
  fc3_kernel<<<(NB * 3 + 255) / 256, 256, 0, stream>>>(
      f3raw, s5, sq5, bn5_g, bn5_b, fc3_w, fc3_b, out);
}